// Round 1
// baseline (703.795 us; speedup 1.0000x reference)
//
#include <hip/hip_runtime.h>

#define B_ 8
#define L_ 512
#define T_ 512
#define D_ 768
#define H_ 12
#define DH_ 64
#define SD_ 5
#define NSW_ 72   // H*(SD+1)

// ---------------------------------------------------------------------------
// Generic SGEMM: C[4096 x N] = A[4096 x 768] @ W[768 x N] + bias, fp32.
// 128x128 tile, BK=8, 256 threads, 8x8 micro-tile in 2x2 quadrants of 4.
// ---------------------------------------------------------------------------
__device__ __forceinline__ void sgemm_body(
    const float* __restrict__ A, const float* __restrict__ W,
    const float* __restrict__ bias, float* __restrict__ C,
    int N, int bx, int by)
{
    __shared__ float As[8][128];
    __shared__ float Bs[8][128];
    const int tid = threadIdx.x;
    const int tx  = tid & 15;
    const int ty  = tid >> 4;

    const int arow = tid >> 1;          // 0..127
    const int acol = (tid & 1) << 2;    // 0 or 4
    const int brow = tid >> 5;          // 0..7
    const int bcol = (tid & 31) << 2;   // 0..124
    const int bN   = bx * 128 + bcol;

    const float* Ap = A + (size_t)(by * 128 + arow) * D_ + acol;

    float acc[8][8];
#pragma unroll
    for (int i = 0; i < 8; i++)
#pragma unroll
        for (int j = 0; j < 8; j++) acc[i][j] = 0.f;

    for (int kb = 0; kb < D_; kb += 8) {
        float4 a4 = *(const float4*)(Ap + kb);
        float4 b4 = make_float4(0.f, 0.f, 0.f, 0.f);
        if (bN + 3 < N) b4 = *(const float4*)(W + (size_t)(kb + brow) * N + bN);
        __syncthreads();
        As[acol + 0][arow] = a4.x;
        As[acol + 1][arow] = a4.y;
        As[acol + 2][arow] = a4.z;
        As[acol + 3][arow] = a4.w;
        *(float4*)&Bs[brow][bcol] = b4;
        __syncthreads();
#pragma unroll
        for (int kk = 0; kk < 8; kk++) {
            float4 a0 = *(const float4*)&As[kk][ty << 2];
            float4 a1 = *(const float4*)&As[kk][64 + (ty << 2)];
            float4 b0 = *(const float4*)&Bs[kk][tx << 2];
            float4 b1 = *(const float4*)&Bs[kk][64 + (tx << 2)];
            float av[8] = {a0.x, a0.y, a0.z, a0.w, a1.x, a1.y, a1.z, a1.w};
            float bv[8] = {b0.x, b0.y, b0.z, b0.w, b1.x, b1.y, b1.z, b1.w};
#pragma unroll
            for (int i = 0; i < 8; i++)
#pragma unroll
                for (int j = 0; j < 8; j++) acc[i][j] += av[i] * bv[j];
        }
    }

    const int c0 = bx * 128 + (tx << 2);
    const int c1 = c0 + 64;
    float4 bias0 = make_float4(0, 0, 0, 0), bias1 = make_float4(0, 0, 0, 0);
    if (c0 + 3 < N) bias0 = *(const float4*)(bias + c0);
    if (c1 + 3 < N) bias1 = *(const float4*)(bias + c1);
#pragma unroll
    for (int i = 0; i < 8; i++) {
        const int r = by * 128 + ((i >> 2) << 6) + (ty << 2) + (i & 3);
        float* Cr = C + (size_t)r * N;
        if (c0 + 3 < N) {
            float4 o = make_float4(acc[i][0] + bias0.x, acc[i][1] + bias0.y,
                                   acc[i][2] + bias0.z, acc[i][3] + bias0.w);
            *(float4*)(Cr + c0) = o;
        }
        if (c1 + 3 < N) {
            float4 o = make_float4(acc[i][4] + bias1.x, acc[i][5] + bias1.y,
                                   acc[i][6] + bias1.z, acc[i][7] + bias1.w);
            *(float4*)(Cr + c1) = o;
        }
    }
}

// z=0: qh = q@Wq+bq  z=1: kh = k@Wk+bk  z=2: vh = v@Wv+bv  z=3: sw = q@Wl+bl
__global__ __launch_bounds__(256) void proj_kernel(
    const float* __restrict__ q, const float* __restrict__ k, const float* __restrict__ v,
    const float* __restrict__ Wq, const float* __restrict__ bq,
    const float* __restrict__ Wk, const float* __restrict__ bk,
    const float* __restrict__ Wv, const float* __restrict__ bv,
    const float* __restrict__ Wl, const float* __restrict__ bl,
    float* __restrict__ qh, float* __restrict__ kh, float* __restrict__ vh,
    float* __restrict__ swv)
{
    const int z = blockIdx.z;
    const float* A; const float* W; const float* bias; float* C; int N;
    if (z == 0)      { A = q; W = Wq; bias = bq; C = qh;  N = D_;   }
    else if (z == 1) { A = k; W = Wk; bias = bk; C = kh;  N = D_;   }
    else if (z == 2) { A = v; W = Wv; bias = bv; C = vh;  N = D_;   }
    else             { A = q; W = Wl; bias = bl; C = swv; N = NSW_; }
    if ((int)blockIdx.x * 128 >= N) return;
    sgemm_body(A, W, bias, C, N, blockIdx.x, blockIdx.y);
}

__global__ __launch_bounds__(256) void final_kernel(
    const float* __restrict__ A, const float* __restrict__ Wf,
    const float* __restrict__ bf, float* __restrict__ out)
{
    sgemm_body(A, Wf, bf, out, D_, blockIdx.x, blockIdx.y);
}

// ---------------------------------------------------------------------------
// Attention: block = (h, b, 64-row l-tile). Streams 32-wide t-tiles.
// p_un = max(sigmoid(w·loc + bias), 1e-6) * exp(qk/8)   (mask -> 0)
// softmax(log(clip(sig)) + attn) == p_un / sum(p_un): max-subtraction cancels
// and logits are small, so exp never overflows.
// Writes unnormalized p to fused (normalized by norm_kernel), normalized PV
// output to out_pre, and per-row sums to `sums`.
// ---------------------------------------------------------------------------
__global__ __launch_bounds__(256) void attn_kernel(
    const float* __restrict__ qhp, const float* __restrict__ khp,
    const float* __restrict__ vhp, const float* __restrict__ swp,
    const float* __restrict__ ploc, const int* __restrict__ maskp,
    float* __restrict__ fused, float* __restrict__ outp,
    float* __restrict__ sums)
{
    const int h  = blockIdx.z;
    const int b  = blockIdx.y;
    const int l0 = blockIdx.x << 6;
    const int tid = threadIdx.x;

    __shared__ float qs[64][65];
    __shared__ float ks[32][65];
    __shared__ float vs[32][64];
    __shared__ float ps[64][33];
    __shared__ float sws[64][6];
    __shared__ float ssum[64];
    __shared__ int   smask[32];

    // stage q tile: 64 rows x 64 cols of head h
    {
        const int r  = tid >> 2;
        const int cq = (tid & 3) << 4;
        const float* src = qhp + (size_t)((b << 9) + l0 + r) * D_ + (h << 6) + cq;
#pragma unroll
        for (int u = 0; u < 4; u++) {
            float4 t4 = *(const float4*)(src + (u << 2));
            qs[r][cq + (u << 2) + 0] = t4.x;
            qs[r][cq + (u << 2) + 1] = t4.y;
            qs[r][cq + (u << 2) + 2] = t4.z;
            qs[r][cq + (u << 2) + 3] = t4.w;
        }
    }
    // spatial weights: col 0 = bias, cols 1..5 = w
    for (int i = tid; i < 64 * 6; i += 256) {
        const int r = i / 6, c = i % 6;
        sws[r][c] = swp[(size_t)((b << 9) + l0 + r) * NSW_ + h * 6 + c];
    }
    if (tid < 64) ssum[tid] = 0.f;

    const int tg = tid & 15;     // 0..15
    const int lg = tid >> 4;     // 0..15
    const int l4 = lg << 2;      // phase A/B row base
    const int t2 = tg << 1;      // phase A t base
    const int d4 = tg << 2;      // phase B col base

    float acc_o[4][4];
#pragma unroll
    for (int i = 0; i < 4; i++)
#pragma unroll
        for (int j = 0; j < 4; j++) acc_o[i][j] = 0.f;

    for (int t0 = 0; t0 < T_; t0 += 32) {
        __syncthreads();   // previous tile's ps/ks/vs fully consumed
        // stage k/v tiles (32 x 64)
        {
            const int r  = tid >> 4;          // 0..15
            const int c4 = (tid & 15) << 2;   // 0..60
            const float* kp = khp + (size_t)((b << 9) + t0 + r) * D_ + (h << 6) + c4;
            const float* vp = vhp + (size_t)((b << 9) + t0 + r) * D_ + (h << 6) + c4;
            float4 ka = *(const float4*)kp;
            float4 kb = *(const float4*)(kp + 16 * D_);
            ks[r][c4 + 0] = ka.x; ks[r][c4 + 1] = ka.y;
            ks[r][c4 + 2] = ka.z; ks[r][c4 + 3] = ka.w;
            ks[r + 16][c4 + 0] = kb.x; ks[r + 16][c4 + 1] = kb.y;
            ks[r + 16][c4 + 2] = kb.z; ks[r + 16][c4 + 3] = kb.w;
            float4 va = *(const float4*)vp;
            float4 vb = *(const float4*)(vp + 16 * D_);
            *(float4*)&vs[r][c4]      = va;
            *(float4*)&vs[r + 16][c4] = vb;
        }
        if (tid < 32) smask[tid] = maskp[(b << 9) + t0 + tid];
        __syncthreads();

        // phase A: qk logits for 4 l x 2 t per thread
        float qk[4][2];
#pragma unroll
        for (int i = 0; i < 4; i++) { qk[i][0] = 0.f; qk[i][1] = 0.f; }
#pragma unroll 4
        for (int kk = 0; kk < 64; kk++) {
            const float kv0 = ks[t2 + 0][kk];
            const float kv1 = ks[t2 + 1][kk];
#pragma unroll
            for (int i = 0; i < 4; i++) {
                const float qv = qs[l4 + i][kk];
                qk[i][0] += qv * kv0;
                qk[i][1] += qv * kv1;
            }
        }
#pragma unroll
        for (int j = 0; j < 2; j++) {
            const int tt  = t2 + j;
            const int msk = smask[tt];
#pragma unroll
            for (int i = 0; i < 4; i++) {
                const int l = l0 + l4 + i;
                const float* pl = ploc + ((size_t)((b << 9) + l) * T_ + (t0 + tt)) * SD_;
                float s = sws[l4 + i][0];
#pragma unroll
                for (int d = 0; d < SD_; d++) s += sws[l4 + i][1 + d] * pl[d];
                const float sig = fmaxf(1.f / (1.f + __expf(-s)), 1e-6f);
                const float p   = msk ? 0.f : sig * __expf(qk[i][j] * 0.125f);
                ps[l4 + i][tt] = p;
            }
        }
        __syncthreads();

        // row sums of this tile
        if (tid < 64) {
            float ssl = 0.f;
#pragma unroll
            for (int t = 0; t < 32; t++) ssl += ps[tid][t];
            ssum[tid] += ssl;
        }

        // phase B: PV accumulate, 4 l x 4 d per thread
#pragma unroll 4
        for (int t = 0; t < 32; t++) {
            const float4 vv = *(const float4*)&vs[t][d4];
            float pv[4];
#pragma unroll
            for (int i = 0; i < 4; i++) pv[i] = ps[l4 + i][t];
#pragma unroll
            for (int i = 0; i < 4; i++) {
                acc_o[i][0] += pv[i] * vv.x;
                acc_o[i][1] += pv[i] * vv.y;
                acc_o[i][2] += pv[i] * vv.z;
                acc_o[i][3] += pv[i] * vv.w;
            }
        }

        // write unnormalized probs
        {
            const int t  = tid & 31;
            const int lb = (tid >> 5) << 3;
            const size_t rowbase = (size_t)((h * B_ + b) * L_ + l0);
#pragma unroll
            for (int e = 0; e < 8; e++) {
                const int l = lb + e;
                fused[(rowbase + l) * T_ + t0 + t] = ps[l][t];
            }
        }
    }
    __syncthreads();

    if (tid < 64) sums[(size_t)((h * B_ + b) * L_) + l0 + tid] = ssum[tid];

#pragma unroll
    for (int i = 0; i < 4; i++) {
        const float inv = 1.f / ssum[l4 + i];
        float4 o;
        o.x = acc_o[i][0] * inv;
        o.y = acc_o[i][1] * inv;
        o.z = acc_o[i][2] * inv;
        o.w = acc_o[i][3] * inv;
        *(float4*)&outp[(size_t)((b << 9) + l0 + l4 + i) * D_ + (h << 6) + d4] = o;
    }
}

// Scale fused_attn in place by 1/rowsum.
__global__ __launch_bounds__(256) void norm_kernel(
    float* __restrict__ fused, const float* __restrict__ sums)
{
    const int gi = blockIdx.x * 256 + threadIdx.x;   // float4 index, T_=512 -> 128 f4/row
    float4* f4 = (float4*)fused;
    float4 v = f4[gi];
    const float inv = 1.f / sums[gi >> 7];
    v.x *= inv; v.y *= inv; v.z *= inv; v.w *= inv;
    f4[gi] = v;
}

// ---------------------------------------------------------------------------
extern "C" void kernel_launch(void* const* d_in, const int* in_sizes, int n_in,
                              void* d_out, int out_size, void* d_ws, size_t ws_size,
                              hipStream_t stream) {
    const float* q    = (const float*)d_in[0];
    const float* k    = (const float*)d_in[1];
    const float* v    = (const float*)d_in[2];
    const float* ploc = (const float*)d_in[3];
    const int*   mask = (const int*)  d_in[4];   // bool -> int32 per harness convention
    const float* Wq   = (const float*)d_in[5];
    const float* bq   = (const float*)d_in[6];
    const float* Wk   = (const float*)d_in[7];
    const float* bk   = (const float*)d_in[8];
    const float* Wv   = (const float*)d_in[9];
    const float* bv   = (const float*)d_in[10];
    const float* Wl   = (const float*)d_in[11];
    const float* bl   = (const float*)d_in[12];
    const float* Wf   = (const float*)d_in[13];
    const float* bf   = (const float*)d_in[14];

    float* ws   = (float*)d_ws;
    float* qh   = ws;                    // 4096*768 = 3145728
    float* kh   = ws + 3145728;          // 3145728
    float* vh   = ws + 6291456;          // 3145728
    float* swv  = ws + 9437184;          // 4096*72  = 294912
    float* outp = ws + 9732096;          // 3145728
    float* sums = ws + 12877824;         // 12*8*512 = 49152  (total ~51.7 MB)

    float* out   = (float*)d_out;                 // [4096 x 768]
    float* fused = out + (size_t)3145728;         // [12*8*512 x 512]

    proj_kernel<<<dim3(6, 32, 4), 256, 0, stream>>>(
        q, k, v, Wq, bq, Wk, bk, Wv, bv, Wl, bl, qh, kh, vh, swv);

    attn_kernel<<<dim3(8, 8, 12), 256, 0, stream>>>(
        qh, kh, vh, swv, ploc, mask, fused, outp, sums);

    norm_kernel<<<dim3(24576), 256, 0, stream>>>(fused, sums);

    final_kernel<<<dim3(6, 32, 1), 256, 0, stream>>>(outp, Wf, bf, out);
}

// Round 2
// 546.857 us; speedup vs baseline: 1.2870x; 1.2870x over previous
//
#include <hip/hip_runtime.h>
#include <hip/hip_bf16.h>

#define B_ 8
#define L_ 512
#define T_ 512
#define D_ 768
#define H_ 12
#define DH_ 64
#define SD_ 5
#define NSW_ 72   // H*(SD+1)
#define K2_ 1536  // split A:  [hi | lo]
#define K3_ 2304  // split W:  [hi | lo | hi]

typedef __attribute__((ext_vector_type(8))) short bf16x8;
typedef __attribute__((ext_vector_type(4))) float f32x4;

__device__ __forceinline__ unsigned short f2bf(float x) {
    union { __hip_bfloat16 h; unsigned short u; } cv;
    cv.h = __float2bfloat16(x);
    return cv.u;
}
__device__ __forceinline__ float bf2f(unsigned short u) {
    union { unsigned short u; __hip_bfloat16 h; } cv;
    cv.u = u;
    return __bfloat162float(cv.h);
}

__device__ __forceinline__ void gload_lds16(const void* g, void* l) {
    __builtin_amdgcn_global_load_lds((const __attribute__((address_space(1))) void*)g,
                                     (__attribute__((address_space(3))) void*)l,
                                     16, 0, 0);
}

// ---------------------------------------------------------------------------
// Split fp32 activations -> A2 = [hi | lo] bf16, row-major [M][1536].
// z: 0=q, 1=k, 2=v
// ---------------------------------------------------------------------------
__global__ __launch_bounds__(256) void asplit_kernel(
    const float* __restrict__ q, const float* __restrict__ k, const float* __restrict__ v,
    short* __restrict__ q2, short* __restrict__ k2, short* __restrict__ v2)
{
    const int z = blockIdx.z;
    const float* A = (z == 0) ? q : (z == 1) ? k : v;
    short* O = (z == 0) ? q2 : (z == 1) ? k2 : v2;
    const int col = blockIdx.x * 256 + threadIdx.x;   // 0..767
    const int m   = blockIdx.y;
    if (col >= D_) return;
    const float a = A[(size_t)m * D_ + col];
    const unsigned short hi = f2bf(a);
    const unsigned short lo = f2bf(a - bf2f(hi));
    O[(size_t)m * K2_ + col]       = (short)hi;
    O[(size_t)m * K2_ + D_ + col]  = (short)lo;
}

// ---------------------------------------------------------------------------
// Transpose + split weights: W [768 x N] fp32 -> WT3 [Npad x 2304] bf16 with
// row n = [hi(W[:,n]) | lo(W[:,n]) | hi(W[:,n])].  z: 0=Wq 1=Wk 2=Wv 3=Wl 4=Wf
// Wl is padded to 128 rows (zeros beyond n=72).
// ---------------------------------------------------------------------------
__global__ __launch_bounds__(256) void wsplit_kernel(
    const float* __restrict__ Wq, const float* __restrict__ Wk,
    const float* __restrict__ Wv, const float* __restrict__ Wl,
    const float* __restrict__ Wf,
    short* __restrict__ WqT3, short* __restrict__ WkT3, short* __restrict__ WvT3,
    short* __restrict__ WlT3, short* __restrict__ WfT3)
{
    const int z = blockIdx.z;
    const float* W; short* O; int Nw, Npad;
    if (z == 0)      { W = Wq; O = WqT3; Nw = D_;   Npad = 768; }
    else if (z == 1) { W = Wk; O = WkT3; Nw = D_;   Npad = 768; }
    else if (z == 2) { W = Wv; O = WvT3; Nw = D_;   Npad = 768; }
    else if (z == 3) { W = Wl; O = WlT3; Nw = NSW_; Npad = 128; }
    else             { W = Wf; O = WfT3; Nw = D_;   Npad = 768; }

    const int k0 = blockIdx.x * 64;
    const int n0 = blockIdx.y * 64;
    if (n0 >= Npad) return;

    __shared__ float sm[64][65];
    const int c  = threadIdx.x & 63;
    const int r4 = threadIdx.x >> 6;

#pragma unroll
    for (int i = 0; i < 16; i++) {
        const int r = i * 4 + r4;
        float val = 0.f;
        if (n0 + c < Nw) val = W[(size_t)(k0 + r) * Nw + n0 + c];
        sm[r][c] = val;
    }
    __syncthreads();

#pragma unroll
    for (int i = 0; i < 16; i++) {
        const int nl = i * 4 + r4;
        const int n  = n0 + nl;
        if (n >= Npad) continue;
        const float v = (n < Nw) ? sm[c][nl] : 0.f;
        const unsigned short hi = f2bf(v);
        const unsigned short lo = f2bf(v - bf2f(hi));
        const size_t rb = (size_t)n * K3_;
        O[rb + k0 + c]        = (short)hi;
        O[rb + 768 + k0 + c]  = (short)lo;
        O[rb + 1536 + k0 + c] = (short)hi;
    }
}

// ---------------------------------------------------------------------------
// MFMA GEMM: C[M x N] = A2[M x 1536] (x) WT3[N x 2304]  (split-bf16, K=2304)
// 128x128 tile, BK=32, 4 waves, each wave 64x64 via 4x4 mfma_f32_16x16x32_bf16.
// zoff+blockIdx.z: 0=qh 1=kh 2=vh 3=swv(Wl,N=72) 4=out(final)
// ---------------------------------------------------------------------------
__global__ __launch_bounds__(256) void mfma_gemm(
    const short* __restrict__ q2, const short* __restrict__ k2, const short* __restrict__ v2,
    const short* __restrict__ WqT3, const short* __restrict__ WkT3,
    const short* __restrict__ WvT3, const short* __restrict__ WlT3,
    const short* __restrict__ WfT3,
    const float* __restrict__ bq, const float* __restrict__ bk,
    const float* __restrict__ bv, const float* __restrict__ bl,
    const float* __restrict__ bf,
    const short* __restrict__ outp2,
    float* __restrict__ qh, float* __restrict__ kh, float* __restrict__ vh,
    float* __restrict__ swv, float* __restrict__ outf,
    int zoff)
{
    const int z = zoff + blockIdx.z;
    const short* A2; const short* WT3; const float* bias; float* C; int Ncols;
    if (z == 0)      { A2 = q2;    WT3 = WqT3; bias = bq; C = qh;   Ncols = D_;   }
    else if (z == 1) { A2 = k2;    WT3 = WkT3; bias = bk; C = kh;   Ncols = D_;   }
    else if (z == 2) { A2 = v2;    WT3 = WvT3; bias = bv; C = vh;   Ncols = D_;   }
    else if (z == 3) { A2 = q2;    WT3 = WlT3; bias = bl; C = swv;  Ncols = NSW_; }
    else             { A2 = outp2; WT3 = WfT3; bias = bf; C = outf; Ncols = D_;   }

    if (z == 3 && blockIdx.x != 0) return;

    const int m0 = blockIdx.y * 128;
    const int n0 = blockIdx.x * 128;

    __shared__ __align__(16) short As[128 * 32];
    __shared__ __align__(16) short Bs[128 * 32];

    const int tid  = threadIdx.x;
    const int lane = tid & 63;
    const int wv_  = tid >> 6;
    const int wm   = (wv_ & 1) << 6;
    const int wn   = (wv_ >> 1) << 6;
    const int l15  = lane & 15;
    const int quad = lane >> 4;

    f32x4 acc[4][4] = {};

    const int sa  = tid;
    const int sb  = tid + 256;
    const int ra  = sa >> 2, ka = (sa & 3) << 3;
    const int rb  = sb >> 2, kb8 = (sb & 3) << 3;

    for (int kb = 0; kb < K3_; kb += 32) {
        const int akb = (kb < 768) ? kb : kb - 768;
        __syncthreads();
        gload_lds16(A2  + (size_t)(m0 + ra) * K2_ + akb + ka,  &As[sa << 3]);
        gload_lds16(A2  + (size_t)(m0 + rb) * K2_ + akb + kb8, &As[sb << 3]);
        gload_lds16(WT3 + (size_t)(n0 + ra) * K3_ + kb  + ka,  &Bs[sa << 3]);
        gload_lds16(WT3 + (size_t)(n0 + rb) * K3_ + kb  + kb8, &Bs[sb << 3]);
        __syncthreads();

        bf16x8 af[4], bfr[4];
#pragma unroll
        for (int t = 0; t < 4; t++) {
            af[t]  = *(const bf16x8*)&As[(wm + t * 16 + l15) * 32 + quad * 8];
            bfr[t] = *(const bf16x8*)&Bs[(wn + t * 16 + l15) * 32 + quad * 8];
        }
#pragma unroll
        for (int mt = 0; mt < 4; mt++)
#pragma unroll
            for (int nt = 0; nt < 4; nt++)
                acc[mt][nt] = __builtin_amdgcn_mfma_f32_16x16x32_bf16(
                    af[mt], bfr[nt], acc[mt][nt], 0, 0, 0);
    }

    // epilogue: C[row][col] = acc + bias[col]
#pragma unroll
    for (int nt = 0; nt < 4; nt++) {
        const int col = n0 + wn + nt * 16 + l15;
        if (col >= Ncols) continue;
        const float bvv = bias[col];
#pragma unroll
        for (int mt = 0; mt < 4; mt++) {
            const int row = m0 + wm + mt * 16 + quad * 4;
#pragma unroll
            for (int r = 0; r < 4; r++)
                C[(size_t)(row + r) * Ncols + col] = acc[mt][nt][r] + bvv;
        }
    }
}

// ---------------------------------------------------------------------------
// Attention (fp32 VALU, unchanged math):
// p_un = max(sigmoid(w·loc + bias), 1e-6) * exp(qk/8)  (mask -> 0)
// writes unnormalized p to fused, row sums to sums, and the normalized PV
// output split into bf16 hi/lo at outp2 [4096 x 1536] for the final MFMA GEMM.
// ---------------------------------------------------------------------------
__global__ __launch_bounds__(256) void attn_kernel(
    const float* __restrict__ qhp, const float* __restrict__ khp,
    const float* __restrict__ vhp, const float* __restrict__ swp,
    const float* __restrict__ ploc, const int* __restrict__ maskp,
    float* __restrict__ fused, short* __restrict__ outp2,
    float* __restrict__ sums)
{
    const int h  = blockIdx.z;
    const int b  = blockIdx.y;
    const int l0 = blockIdx.x << 6;
    const int tid = threadIdx.x;

    __shared__ float qs[64][65];
    __shared__ float ks[32][65];
    __shared__ float vs[32][64];
    __shared__ float ps[64][33];
    __shared__ float sws[64][6];
    __shared__ float ssum[64];
    __shared__ int   smask[32];

    {
        const int r  = tid >> 2;
        const int cq = (tid & 3) << 4;
        const float* src = qhp + (size_t)((b << 9) + l0 + r) * D_ + (h << 6) + cq;
#pragma unroll
        for (int u = 0; u < 4; u++) {
            float4 t4 = *(const float4*)(src + (u << 2));
            qs[r][cq + (u << 2) + 0] = t4.x;
            qs[r][cq + (u << 2) + 1] = t4.y;
            qs[r][cq + (u << 2) + 2] = t4.z;
            qs[r][cq + (u << 2) + 3] = t4.w;
        }
    }
    for (int i = tid; i < 64 * 6; i += 256) {
        const int r = i / 6, c = i % 6;
        sws[r][c] = swp[(size_t)((b << 9) + l0 + r) * NSW_ + h * 6 + c];
    }
    if (tid < 64) ssum[tid] = 0.f;

    const int tg = tid & 15;
    const int lg = tid >> 4;
    const int l4 = lg << 2;
    const int t2 = tg << 1;
    const int d4 = tg << 2;

    float acc_o[4][4];
#pragma unroll
    for (int i = 0; i < 4; i++)
#pragma unroll
        for (int j = 0; j < 4; j++) acc_o[i][j] = 0.f;

    for (int t0 = 0; t0 < T_; t0 += 32) {
        __syncthreads();
        {
            const int r  = tid >> 4;
            const int c4 = (tid & 15) << 2;
            const float* kp = khp + (size_t)((b << 9) + t0 + r) * D_ + (h << 6) + c4;
            const float* vp = vhp + (size_t)((b << 9) + t0 + r) * D_ + (h << 6) + c4;
            float4 ka = *(const float4*)kp;
            float4 kbv = *(const float4*)(kp + 16 * D_);
            ks[r][c4 + 0] = ka.x; ks[r][c4 + 1] = ka.y;
            ks[r][c4 + 2] = ka.z; ks[r][c4 + 3] = ka.w;
            ks[r + 16][c4 + 0] = kbv.x; ks[r + 16][c4 + 1] = kbv.y;
            ks[r + 16][c4 + 2] = kbv.z; ks[r + 16][c4 + 3] = kbv.w;
            float4 va = *(const float4*)vp;
            float4 vb = *(const float4*)(vp + 16 * D_);
            *(float4*)&vs[r][c4]      = va;
            *(float4*)&vs[r + 16][c4] = vb;
        }
        if (tid < 32) smask[tid] = maskp[(b << 9) + t0 + tid];
        __syncthreads();

        float qk[4][2];
#pragma unroll
        for (int i = 0; i < 4; i++) { qk[i][0] = 0.f; qk[i][1] = 0.f; }
#pragma unroll 4
        for (int kk = 0; kk < 64; kk++) {
            const float kv0 = ks[t2 + 0][kk];
            const float kv1 = ks[t2 + 1][kk];
#pragma unroll
            for (int i = 0; i < 4; i++) {
                const float qv = qs[l4 + i][kk];
                qk[i][0] += qv * kv0;
                qk[i][1] += qv * kv1;
            }
        }
#pragma unroll
        for (int j = 0; j < 2; j++) {
            const int tt  = t2 + j;
            const int msk = smask[tt];
#pragma unroll
            for (int i = 0; i < 4; i++) {
                const int l = l0 + l4 + i;
                const float* pl = ploc + ((size_t)((b << 9) + l) * T_ + (t0 + tt)) * SD_;
                float s = sws[l4 + i][0];
#pragma unroll
                for (int d = 0; d < SD_; d++) s += sws[l4 + i][1 + d] * pl[d];
                const float sig = fmaxf(1.f / (1.f + __expf(-s)), 1e-6f);
                const float p   = msk ? 0.f : sig * __expf(qk[i][j] * 0.125f);
                ps[l4 + i][tt] = p;
            }
        }
        __syncthreads();

        if (tid < 64) {
            float ssl = 0.f;
#pragma unroll
            for (int t = 0; t < 32; t++) ssl += ps[tid][t];
            ssum[tid] += ssl;
        }

#pragma unroll 4
        for (int t = 0; t < 32; t++) {
            const float4 vv = *(const float4*)&vs[t][d4];
            float pv[4];
#pragma unroll
            for (int i = 0; i < 4; i++) pv[i] = ps[l4 + i][t];
#pragma unroll
            for (int i = 0; i < 4; i++) {
                acc_o[i][0] += pv[i] * vv.x;
                acc_o[i][1] += pv[i] * vv.y;
                acc_o[i][2] += pv[i] * vv.z;
                acc_o[i][3] += pv[i] * vv.w;
            }
        }

        {
            const int t  = tid & 31;
            const int lb = (tid >> 5) << 3;
            const size_t rowbase = (size_t)((h * B_ + b) * L_ + l0);
#pragma unroll
            for (int e = 0; e < 8; e++) {
                const int l = lb + e;
                fused[(rowbase + l) * T_ + t0 + t] = ps[l][t];
            }
        }
    }
    __syncthreads();

    if (tid < 64) sums[(size_t)((h * B_ + b) * L_) + l0 + tid] = ssum[tid];

#pragma unroll
    for (int i = 0; i < 4; i++) {
        const float inv = 1.f / ssum[l4 + i];
        const size_t base = (size_t)((b << 9) + l0 + l4 + i) * K2_ + (h << 6) + d4;
#pragma unroll
        for (int j = 0; j < 4; j++) {
            const float val = acc_o[i][j] * inv;
            const unsigned short hi = f2bf(val);
            const unsigned short lo = f2bf(val - bf2f(hi));
            outp2[base + j]       = (short)hi;
            outp2[base + D_ + j]  = (short)lo;
        }
    }
}

// Scale fused_attn in place by 1/rowsum.
__global__ __launch_bounds__(256) void norm_kernel(
    float* __restrict__ fused, const float* __restrict__ sums)
{
    const int gi = blockIdx.x * 256 + threadIdx.x;
    float4* f4 = (float4*)fused;
    float4 v = f4[gi];
    const float inv = 1.f / sums[gi >> 7];
    v.x *= inv; v.y *= inv; v.z *= inv; v.w *= inv;
    f4[gi] = v;
}

// ---------------------------------------------------------------------------
extern "C" void kernel_launch(void* const* d_in, const int* in_sizes, int n_in,
                              void* d_out, int out_size, void* d_ws, size_t ws_size,
                              hipStream_t stream) {
    const float* q    = (const float*)d_in[0];
    const float* k    = (const float*)d_in[1];
    const float* v    = (const float*)d_in[2];
    const float* ploc = (const float*)d_in[3];
    const int*   mask = (const int*)  d_in[4];
    const float* Wq   = (const float*)d_in[5];
    const float* bq   = (const float*)d_in[6];
    const float* Wk   = (const float*)d_in[7];
    const float* bk   = (const float*)d_in[8];
    const float* Wv   = (const float*)d_in[9];
    const float* bv   = (const float*)d_in[10];
    const float* Wl   = (const float*)d_in[11];
    const float* bl   = (const float*)d_in[12];
    const float* Wf   = (const float*)d_in[13];
    const float* bf   = (const float*)d_in[14];

    char* p = (char*)d_ws;
    short* q2    = (short*)p; p += (size_t)4096 * K2_ * 2;   // 12.58 MB (reused as outp2)
    short* k2    = (short*)p; p += (size_t)4096 * K2_ * 2;
    short* v2    = (short*)p; p += (size_t)4096 * K2_ * 2;
    short* WqT3  = (short*)p; p += (size_t)768 * K3_ * 2;
    short* WkT3  = (short*)p; p += (size_t)768 * K3_ * 2;
    short* WvT3  = (short*)p; p += (size_t)768 * K3_ * 2;
    short* WlT3  = (short*)p; p += (size_t)128 * K3_ * 2;
    short* WfT3  = (short*)p; p += (size_t)768 * K3_ * 2;
    float* qh    = (float*)p; p += (size_t)4096 * D_ * 4;
    float* kh    = (float*)p; p += (size_t)4096 * D_ * 4;
    float* vh    = (float*)p; p += (size_t)4096 * D_ * 4;
    float* swv   = (float*)p; p += (size_t)4096 * NSW_ * 4;
    float* sums  = (float*)p; p += (size_t)H_ * B_ * L_ * 4;
    short* outp2 = q2;   // q2 dead after proj GEMMs; attn writes outp2 here

    float* out   = (float*)d_out;
    float* fused = out + (size_t)4096 * D_;

    asplit_kernel<<<dim3(3, 4096, 3), 256, 0, stream>>>(q, k, v, q2, k2, v2);
    wsplit_kernel<<<dim3(12, 12, 5), 256, 0, stream>>>(
        Wq, Wk, Wv, Wl, Wf, WqT3, WkT3, WvT3, WlT3, WfT3);

    mfma_gemm<<<dim3(6, 32, 4), 256, 0, stream>>>(
        q2, k2, v2, WqT3, WkT3, WvT3, WlT3, WfT3,
        bq, bk, bv, bl, bf, outp2, qh, kh, vh, swv, out, 0);

    attn_kernel<<<dim3(8, 8, 12), 256, 0, stream>>>(
        qh, kh, vh, swv, ploc, mask, fused, outp2, sums);

    norm_kernel<<<dim3(24576), 256, 0, stream>>>(fused, sums);

    mfma_gemm<<<dim3(6, 32, 1), 256, 0, stream>>>(
        q2, k2, v2, WqT3, WkT3, WvT3, WlT3, WfT3,
        bq, bk, bv, bl, bf, outp2, qh, kh, vh, swv, out, 4);
}

// Round 3
// 511.411 us; speedup vs baseline: 1.3762x; 1.0693x over previous
//
#include <hip/hip_runtime.h>
#include <hip/hip_bf16.h>

#define B_ 8
#define L_ 512
#define T_ 512
#define D_ 768
#define H_ 12
#define DH_ 64
#define SD_ 5
#define NSW_ 72   // H*(SD+1)
#define K2_ 1536  // split A:  [hi | lo]
#define K3_ 2304  // split W:  [hi | lo | hi]

typedef __attribute__((ext_vector_type(8))) short bf16x8;
typedef __attribute__((ext_vector_type(4))) float f32x4;
typedef unsigned short ushort_t;

__device__ __forceinline__ unsigned short f2bf(float x) {
    union { __hip_bfloat16 h; unsigned short u; } cv;
    cv.h = __float2bfloat16(x);
    return cv.u;
}
__device__ __forceinline__ float bf2f(unsigned short u) {
    union { unsigned short u; __hip_bfloat16 h; } cv;
    cv.u = u;
    return __bfloat162float(cv.h);
}

__device__ __forceinline__ void gload_lds16(const void* g, void* l) {
    __builtin_amdgcn_global_load_lds((const __attribute__((address_space(1))) void*)g,
                                     (__attribute__((address_space(3))) void*)l,
                                     16, 0, 0);
}

// ---------------------------------------------------------------------------
// Split fp32 activations -> A2 = [hi | lo] bf16, row-major [M][1536].
// ---------------------------------------------------------------------------
__global__ __launch_bounds__(256) void asplit_kernel(
    const float* __restrict__ q, const float* __restrict__ k, const float* __restrict__ v,
    short* __restrict__ q2, short* __restrict__ k2, short* __restrict__ v2)
{
    const int z = blockIdx.z;
    const float* A = (z == 0) ? q : (z == 1) ? k : v;
    short* O = (z == 0) ? q2 : (z == 1) ? k2 : v2;
    const int col = blockIdx.x * 256 + threadIdx.x;
    const int m   = blockIdx.y;
    if (col >= D_) return;
    const float a = A[(size_t)m * D_ + col];
    const unsigned short hi = f2bf(a);
    const unsigned short lo = f2bf(a - bf2f(hi));
    O[(size_t)m * K2_ + col]       = (short)hi;
    O[(size_t)m * K2_ + D_ + col]  = (short)lo;
}

// ---------------------------------------------------------------------------
// Transpose + split weights -> WT3 [Npad x 2304]: row n = [hi | lo | hi].
// ---------------------------------------------------------------------------
__global__ __launch_bounds__(256) void wsplit_kernel(
    const float* __restrict__ Wq, const float* __restrict__ Wk,
    const float* __restrict__ Wv, const float* __restrict__ Wl,
    const float* __restrict__ Wf,
    short* __restrict__ WqT3, short* __restrict__ WkT3, short* __restrict__ WvT3,
    short* __restrict__ WlT3, short* __restrict__ WfT3)
{
    const int z = blockIdx.z;
    const float* W; short* O; int Nw, Npad;
    if (z == 0)      { W = Wq; O = WqT3; Nw = D_;   Npad = 768; }
    else if (z == 1) { W = Wk; O = WkT3; Nw = D_;   Npad = 768; }
    else if (z == 2) { W = Wv; O = WvT3; Nw = D_;   Npad = 768; }
    else if (z == 3) { W = Wl; O = WlT3; Nw = NSW_; Npad = 128; }
    else             { W = Wf; O = WfT3; Nw = D_;   Npad = 768; }

    const int k0 = blockIdx.x * 64;
    const int n0 = blockIdx.y * 64;
    if (n0 >= Npad) return;

    __shared__ float sm[64][65];
    const int c  = threadIdx.x & 63;
    const int r4 = threadIdx.x >> 6;

#pragma unroll
    for (int i = 0; i < 16; i++) {
        const int r = i * 4 + r4;
        float val = 0.f;
        if (n0 + c < Nw) val = W[(size_t)(k0 + r) * Nw + n0 + c];
        sm[r][c] = val;
    }
    __syncthreads();

#pragma unroll
    for (int i = 0; i < 16; i++) {
        const int nl = i * 4 + r4;
        const int n  = n0 + nl;
        if (n >= Npad) continue;
        const float v = (n < Nw) ? sm[c][nl] : 0.f;
        const unsigned short hi = f2bf(v);
        const unsigned short lo = f2bf(v - bf2f(hi));
        const size_t rb = (size_t)n * K3_;
        O[rb + k0 + c]        = (short)hi;
        O[rb + 768 + k0 + c]  = (short)lo;
        O[rb + 1536 + k0 + c] = (short)hi;
    }
}

// ---------------------------------------------------------------------------
// MFMA GEMM (split-bf16, K=2304). Epilogues per z:
//  z=0: qs2a [h][b][l][hi64|lo64]   z=1: ks2a [h][b][t][hi64|lo64]
//  z=2: vt2  [h][b][dd(hi) / 64+dd(lo)][t]   z=3: swv fp32 [4096][72]
//  z=4: out fp32 [4096][768]
// ---------------------------------------------------------------------------
__global__ __launch_bounds__(256) void mfma_gemm(
    const short* __restrict__ q2, const short* __restrict__ k2, const short* __restrict__ v2,
    const short* __restrict__ WqT3, const short* __restrict__ WkT3,
    const short* __restrict__ WvT3, const short* __restrict__ WlT3,
    const short* __restrict__ WfT3,
    const float* __restrict__ bq, const float* __restrict__ bk,
    const float* __restrict__ bv, const float* __restrict__ bl,
    const float* __restrict__ bf,
    const short* __restrict__ outp2,
    ushort_t* __restrict__ qs2a, ushort_t* __restrict__ ks2a, ushort_t* __restrict__ vt2,
    float* __restrict__ swv, float* __restrict__ outf,
    int zoff)
{
    const int z = zoff + blockIdx.z;
    const short* A2; const short* WT3; const float* bias;
    if (z == 0)      { A2 = q2;    WT3 = WqT3; bias = bq; }
    else if (z == 1) { A2 = k2;    WT3 = WkT3; bias = bk; }
    else if (z == 2) { A2 = v2;    WT3 = WvT3; bias = bv; }
    else if (z == 3) { A2 = q2;    WT3 = WlT3; bias = bl; }
    else             { A2 = outp2; WT3 = WfT3; bias = bf; }

    if (z == 3 && blockIdx.x != 0) return;

    const int m0 = blockIdx.y * 128;
    const int n0 = blockIdx.x * 128;

    __shared__ __align__(16) short As[128 * 32];
    __shared__ __align__(16) short Bs[128 * 32];

    const int tid  = threadIdx.x;
    const int lane = tid & 63;
    const int wv_  = tid >> 6;
    const int wm   = (wv_ & 1) << 6;
    const int wn   = (wv_ >> 1) << 6;
    const int l15  = lane & 15;
    const int quad = lane >> 4;

    f32x4 acc[4][4] = {};

    const int sa  = tid;
    const int sb  = tid + 256;
    const int ra  = sa >> 2, ka = (sa & 3) << 3;
    const int rb  = sb >> 2, kb8 = (sb & 3) << 3;

    for (int kb = 0; kb < K3_; kb += 32) {
        const int akb = (kb < 768) ? kb : kb - 768;
        __syncthreads();
        gload_lds16(A2  + (size_t)(m0 + ra) * K2_ + akb + ka,  &As[sa << 3]);
        gload_lds16(A2  + (size_t)(m0 + rb) * K2_ + akb + kb8, &As[sb << 3]);
        gload_lds16(WT3 + (size_t)(n0 + ra) * K3_ + kb  + ka,  &Bs[sa << 3]);
        gload_lds16(WT3 + (size_t)(n0 + rb) * K3_ + kb  + kb8, &Bs[sb << 3]);
        __syncthreads();

        bf16x8 af[4], bfr[4];
#pragma unroll
        for (int t = 0; t < 4; t++) {
            af[t]  = *(const bf16x8*)&As[(wm + t * 16 + l15) * 32 + quad * 8];
            bfr[t] = *(const bf16x8*)&Bs[(wn + t * 16 + l15) * 32 + quad * 8];
        }
#pragma unroll
        for (int mt = 0; mt < 4; mt++)
#pragma unroll
            for (int nt = 0; nt < 4; nt++)
                acc[mt][nt] = __builtin_amdgcn_mfma_f32_16x16x32_bf16(
                    af[mt], bfr[nt], acc[mt][nt], 0, 0, 0);
    }

    if (z <= 2) {
        ushort_t* dst = (z == 0) ? qs2a : (z == 1) ? ks2a : vt2;
#pragma unroll
        for (int nt = 0; nt < 4; nt++) {
            const int col = n0 + wn + nt * 16 + l15;
            const int hh = col >> 6, dd = col & 63;
            const float bvv = bias[col];
#pragma unroll
            for (int mt = 0; mt < 4; mt++) {
                const int rowb = m0 + wm + mt * 16 + quad * 4;
                if (z < 2) {
#pragma unroll
                    for (int r = 0; r < 4; r++) {
                        const int gr = rowb + r;
                        const int bb = gr >> 9, ll = gr & 511;
                        const float x = acc[mt][nt][r] + bvv;
                        const ushort_t hi = f2bf(x);
                        const ushort_t lo = f2bf(x - bf2f(hi));
                        const size_t base = (((size_t)hh * B_ + bb) * 512 + ll) * 128 + dd;
                        dst[base]      = hi;
                        dst[base + 64] = lo;
                    }
                } else {
                    const int bb = rowb >> 9, tt = rowb & 511;
                    ushort_t hi4[4], lo4[4];
#pragma unroll
                    for (int r = 0; r < 4; r++) {
                        const float x = acc[mt][nt][r] + bvv;
                        hi4[r] = f2bf(x);
                        lo4[r] = f2bf(x - bf2f(hi4[r]));
                    }
                    const size_t base = (((size_t)hh * B_ + bb) * 128 + dd) * 512 + tt;
                    *(ushort4*)&dst[base]            = *(ushort4*)hi4;
                    *(ushort4*)&dst[base + 64 * 512] = *(ushort4*)lo4;
                }
            }
        }
    } else if (z == 3) {
#pragma unroll
        for (int nt = 0; nt < 4; nt++) {
            const int col = n0 + wn + nt * 16 + l15;
            if (col >= NSW_) continue;
            const float bvv = bias[col];
#pragma unroll
            for (int mt = 0; mt < 4; mt++) {
                const int row = m0 + wm + mt * 16 + quad * 4;
#pragma unroll
                for (int r = 0; r < 4; r++)
                    swv[(size_t)(row + r) * NSW_ + col] = acc[mt][nt][r] + bvv;
            }
        }
    } else {
#pragma unroll
        for (int nt = 0; nt < 4; nt++) {
            const int col = n0 + wn + nt * 16 + l15;
            const float bvv = bias[col];
#pragma unroll
            for (int mt = 0; mt < 4; mt++) {
                const int row = m0 + wm + mt * 16 + quad * 4;
#pragma unroll
                for (int r = 0; r < 4; r++)
                    outf[(size_t)(row + r) * D_ + col] = acc[mt][nt][r] + bvv;
            }
        }
    }
}

// ---------------------------------------------------------------------------
// sig16[h][b][l][t] = mask ? 0 : max(sigmoid(bias_h + w_h · ploc[b,l,t,:]), 1e-6)
// One block per (b,l): reads ploc exactly once device-wide.
// ---------------------------------------------------------------------------
__global__ __launch_bounds__(256) void sig_kernel(
    const float* __restrict__ ploc, const float* __restrict__ swv,
    const int* __restrict__ maskp, _Float16* __restrict__ sig16)
{
    const int b = blockIdx.y;
    const int l = blockIdx.x;
    const int tid = threadIdx.x;

    __shared__ float pls[512 * 5];
    __shared__ float sws[72];
    __shared__ int   msk[512];

    const float* src = ploc + (size_t)(b * 512 + l) * 512 * 5;
    for (int i = tid; i < 640; i += 256)
        *(float4*)&pls[i * 4] = *(const float4*)(src + i * 4);
    if (tid < 72) sws[tid] = swv[(size_t)(b * 512 + l) * NSW_ + tid];
    for (int i = tid; i < 512; i += 256) msk[i] = maskp[b * 512 + i];
    __syncthreads();

    for (int e = tid; e < H_ * 512; e += 256) {
        const int t  = e & 511;
        const int hh = e >> 9;
        float s = sws[hh * 6];
#pragma unroll
        for (int d = 0; d < SD_; d++) s += sws[hh * 6 + 1 + d] * pls[t * 5 + d];
        const float sig = msk[t] ? 0.f : fmaxf(1.f / (1.f + __expf(-s)), 1e-6f);
        sig16[(((size_t)hh * B_ + b) * 512 + l) * 512 + t] = (_Float16)sig;
    }
}

// ---------------------------------------------------------------------------
// MFMA attention. Block = (h, b, 64-l-tile); iterates 64-wide t-tiles.
// QK: split-bf16 3-term (K=192 effective). P -> LDS (padded) -> A-frag for PV
// (3-term vs split V^T). Row sums accumulate during the coalesced fused-store.
// ---------------------------------------------------------------------------
__global__ __launch_bounds__(256) void attn_kernel(
    const ushort_t* __restrict__ qs2, const ushort_t* __restrict__ ks2,
    const ushort_t* __restrict__ vt2, const _Float16* __restrict__ sig16,
    float* __restrict__ fused, ushort_t* __restrict__ outp2,
    float* __restrict__ sums)
{
    const int h  = blockIdx.z;
    const int b  = blockIdx.y;
    const int l0 = blockIdx.x << 6;
    const int hb = h * B_ + b;
    const int tid  = threadIdx.x;
    const int lane = tid & 63;
    const int wv   = tid >> 6;
    const int l15  = lane & 15;
    const int quad = lane >> 4;

    __shared__ __align__(16) ushort_t qs[64 * 128];
    __shared__ __align__(16) ushort_t ks[64 * 128];
    __shared__ __align__(16) ushort_t vts[128 * 64];
    __shared__ __align__(16) ushort_t ps[64 * 136];   // [l][hi 0-63 | lo 64-127 | pad]
    __shared__ float ssb[4 * 64];
    __shared__ float ssum[64];

    // stage Q tile (swizzled chunks: LDS chunk i holds global chunk (c ^ (r&7)))
    {
        const size_t qbase = ((size_t)hb * 512 + l0) * 128;
#pragma unroll
        for (int j = 0; j < 4; j++) {
            const int i = tid + 256 * j;
            const int r = i >> 4, c = i & 15, gc = c ^ (r & 7);
            gload_lds16(qs2 + qbase + r * 128 + gc * 8, &qs[i * 8]);
        }
    }

    float pacc = 0.f;
    f32x4 accpv[4] = {};

    for (int t0 = 0; t0 < T_; t0 += 64) {
        __syncthreads();
        {
            const size_t kbase = ((size_t)hb * 512 + t0) * 128;
#pragma unroll
            for (int j = 0; j < 4; j++) {
                const int i = tid + 256 * j;
                const int r = i >> 4, c = i & 15, gc = c ^ (r & 7);
                gload_lds16(ks2 + kbase + r * 128 + gc * 8, &ks[i * 8]);
            }
            const size_t vbase = (size_t)hb * 128 * 512;
#pragma unroll
            for (int j = 0; j < 4; j++) {
                const int i = tid + 256 * j;
                const int r = i >> 3, c = i & 7, gc = c ^ (r & 7);
                gload_lds16(vt2 + vbase + (size_t)r * 512 + t0 + gc * 8, &vts[i * 8]);
            }
        }
        __syncthreads();

        // prefetch sig values for this wave's 64x16 S-slice
        float sigv[4][4];
        {
            const _Float16* sgp = sig16 + (((size_t)hb * 512 + l0) * 512) + t0 + wv * 16 + l15;
#pragma unroll
            for (int mt = 0; mt < 4; mt++)
#pragma unroll
                for (int r2 = 0; r2 < 4; r2++)
                    sigv[mt][r2] = (float)sgp[(size_t)(mt * 16 + quad * 4 + r2) * 512];
        }

        // ---- QK: S[64 l x 16 t per wave] ----
        f32x4 acq[4] = {};
        {
            const int trow = wv * 16 + l15;
            const int tsw  = trow & 7;
            const bf16x8 bk0 = *(const bf16x8*)&ks[trow * 128 + ((0  + quad) ^ tsw) * 8];
            const bf16x8 bk1 = *(const bf16x8*)&ks[trow * 128 + ((4  + quad) ^ tsw) * 8];
            const bf16x8 bk2 = *(const bf16x8*)&ks[trow * 128 + ((8  + quad) ^ tsw) * 8];
            const bf16x8 bk3 = *(const bf16x8*)&ks[trow * 128 + ((12 + quad) ^ tsw) * 8];
#pragma unroll
            for (int mt = 0; mt < 4; mt++) {
                const int arow = mt * 16 + l15;
                const int asw  = arow & 7;
                const bf16x8 a0 = *(const bf16x8*)&qs[arow * 128 + ((0  + quad) ^ asw) * 8];
                const bf16x8 a1 = *(const bf16x8*)&qs[arow * 128 + ((4  + quad) ^ asw) * 8];
                const bf16x8 a2 = *(const bf16x8*)&qs[arow * 128 + ((8  + quad) ^ asw) * 8];
                const bf16x8 a3 = *(const bf16x8*)&qs[arow * 128 + ((12 + quad) ^ asw) * 8];
                f32x4 a = acq[mt];
                a = __builtin_amdgcn_mfma_f32_16x16x32_bf16(a0, bk0, a, 0, 0, 0); // hi.hi
                a = __builtin_amdgcn_mfma_f32_16x16x32_bf16(a1, bk1, a, 0, 0, 0);
                a = __builtin_amdgcn_mfma_f32_16x16x32_bf16(a0, bk2, a, 0, 0, 0); // hi.lo
                a = __builtin_amdgcn_mfma_f32_16x16x32_bf16(a1, bk3, a, 0, 0, 0);
                a = __builtin_amdgcn_mfma_f32_16x16x32_bf16(a2, bk0, a, 0, 0, 0); // lo.hi
                a = __builtin_amdgcn_mfma_f32_16x16x32_bf16(a3, bk1, a, 0, 0, 0);
                acq[mt] = a;
            }
        }

        // ---- p = sig * exp(qk/8), split to LDS ----
        {
            const int tcol = wv * 16 + l15;
#pragma unroll
            for (int mt = 0; mt < 4; mt++)
#pragma unroll
                for (int r2 = 0; r2 < 4; r2++) {
                    const int lrow = mt * 16 + quad * 4 + r2;
                    const float p  = sigv[mt][r2] * __expf(acq[mt][r2] * 0.125f);
                    const ushort_t hi = f2bf(p);
                    const ushort_t lo = f2bf(p - bf2f(hi));
                    ps[lrow * 136 + tcol]      = hi;
                    ps[lrow * 136 + 64 + tcol] = lo;
                }
        }
        __syncthreads();

        // ---- fused store (coalesced) + row-sum partials ----
        {
            const int row = tid >> 2, c4 = tid & 3;
            float vbuf[16];
            float s = 0.f;
#pragma unroll
            for (int jj = 0; jj < 16; jj++) {
                const int t = c4 * 16 + jj;
                const float pv = bf2f(ps[row * 136 + t]) + bf2f(ps[row * 136 + 64 + t]);
                vbuf[jj] = pv;
                s += pv;
            }
            pacc += s;
            float* dstf = fused + ((size_t)hb * 512 + l0 + row) * 512 + t0 + c4 * 16;
#pragma unroll
            for (int jj = 0; jj < 4; jj++)
                *(float4*)(dstf + jj * 4) = *(float4*)&vbuf[jj * 4];
        }

        // ---- PV: out[64 l x 16 d per wave] += P * V ----
        {
            const int vrh = wv * 16 + l15;
            const int vrl = 64 + vrh;
            const int swh = vrh & 7, swl = vrl & 7;
            const bf16x8 bh0 = *(const bf16x8*)&vts[vrh * 64 + ((0 + quad) ^ swh) * 8];
            const bf16x8 bh1 = *(const bf16x8*)&vts[vrh * 64 + ((4 + quad) ^ swh) * 8];
            const bf16x8 bl0 = *(const bf16x8*)&vts[vrl * 64 + ((0 + quad) ^ swl) * 8];
            const bf16x8 bl1 = *(const bf16x8*)&vts[vrl * 64 + ((4 + quad) ^ swl) * 8];
#pragma unroll
            for (int mt = 0; mt < 4; mt++) {
                const int prow = mt * 16 + l15;
                const bf16x8 ph0 = *(const bf16x8*)&ps[prow * 136 + 0  + quad * 8];
                const bf16x8 ph1 = *(const bf16x8*)&ps[prow * 136 + 32 + quad * 8];
                const bf16x8 pl0 = *(const bf16x8*)&ps[prow * 136 + 64 + quad * 8];
                const bf16x8 pl1 = *(const bf16x8*)&ps[prow * 136 + 96 + quad * 8];
                f32x4 a = accpv[mt];
                a = __builtin_amdgcn_mfma_f32_16x16x32_bf16(ph0, bh0, a, 0, 0, 0); // Phi.Vhi
                a = __builtin_amdgcn_mfma_f32_16x16x32_bf16(ph1, bh1, a, 0, 0, 0);
                a = __builtin_amdgcn_mfma_f32_16x16x32_bf16(ph0, bl0, a, 0, 0, 0); // Phi.Vlo
                a = __builtin_amdgcn_mfma_f32_16x16x32_bf16(ph1, bl1, a, 0, 0, 0);
                a = __builtin_amdgcn_mfma_f32_16x16x32_bf16(pl0, bh0, a, 0, 0, 0); // Plo.Vhi
                a = __builtin_amdgcn_mfma_f32_16x16x32_bf16(pl1, bh1, a, 0, 0, 0);
                accpv[mt] = a;
            }
        }
    }

    __syncthreads();
    ssb[(tid & 3) * 64 + (tid >> 2)] = pacc;
    __syncthreads();
    if (tid < 64) {
        const float s = ssb[tid] + ssb[64 + tid] + ssb[128 + tid] + ssb[192 + tid];
        ssum[tid] = s;
        sums[(size_t)hb * 512 + l0 + tid] = s;
    }
    __syncthreads();

#pragma unroll
    for (int mt = 0; mt < 4; mt++)
#pragma unroll
        for (int r2 = 0; r2 < 4; r2++) {
            const int lrow = mt * 16 + quad * 4 + r2;
            const float val = accpv[mt][r2] / ssum[lrow];
            const ushort_t hi = f2bf(val);
            const ushort_t lo = f2bf(val - bf2f(hi));
            const size_t obase = ((size_t)(b * 512 + l0 + lrow)) * K2_ + h * 64 + wv * 16 + l15;
            outp2[obase]       = hi;
            outp2[obase + D_]  = lo;
        }
}

// Scale fused_attn in place by 1/rowsum.
__global__ __launch_bounds__(256) void norm_kernel(
    float* __restrict__ fused, const float* __restrict__ sums)
{
    const int gi = blockIdx.x * 256 + threadIdx.x;
    float4* f4 = (float4*)fused;
    float4 v = f4[gi];
    const float inv = 1.f / sums[gi >> 7];
    v.x *= inv; v.y *= inv; v.z *= inv; v.w *= inv;
    f4[gi] = v;
}

// ---------------------------------------------------------------------------
extern "C" void kernel_launch(void* const* d_in, const int* in_sizes, int n_in,
                              void* d_out, int out_size, void* d_ws, size_t ws_size,
                              hipStream_t stream) {
    const float* q    = (const float*)d_in[0];
    const float* k    = (const float*)d_in[1];
    const float* v    = (const float*)d_in[2];
    const float* ploc = (const float*)d_in[3];
    const int*   mask = (const int*)  d_in[4];
    const float* Wq   = (const float*)d_in[5];
    const float* bq   = (const float*)d_in[6];
    const float* Wk   = (const float*)d_in[7];
    const float* bk   = (const float*)d_in[8];
    const float* Wv   = (const float*)d_in[9];
    const float* bv   = (const float*)d_in[10];
    const float* Wl   = (const float*)d_in[11];
    const float* bl   = (const float*)d_in[12];
    const float* Wf   = (const float*)d_in[13];
    const float* bf   = (const float*)d_in[14];

    // Arena. sig16 (50.33 MB) overlays [q2..WlT3 + gap] which are dead after
    // the projection GEMMs. WfT3 and later regions stay live.
    char* base = (char*)d_ws;
    short*    q2    = (short*)(base + 0);            // 12,582,912 B
    short*    k2    = (short*)(base + 12582912);
    short*    v2    = (short*)(base + 25165824);
    short*    WqT3  = (short*)(base + 37748736);     //  3,538,944 B
    short*    WkT3  = (short*)(base + 41287680);
    short*    WvT3  = (short*)(base + 44826624);
    short*    WlT3  = (short*)(base + 48365568);     //    589,824 B
    _Float16* sig16 = (_Float16*)(base + 0);         // 50,331,648 B overlay
    short*    WfT3  = (short*)(base + 50331648);
    ushort_t* qs2a  = (ushort_t*)(base + 53870592);  // 12,582,912 B
    ushort_t* ks2a  = (ushort_t*)(base + 66453504);
    ushort_t* vt2   = (ushort_t*)(base + 79036416);
    float*    swv   = (float*)(base + 91619328);     //  1,179,648 B
    float*    sums  = (float*)(base + 92798976);     //    196,608 B
    short*    outp2 = (short*)(base + 92995584);     // 12,582,912 B -> 105,578,496 total

    float* out   = (float*)d_out;
    float* fused = out + (size_t)4096 * D_;

    asplit_kernel<<<dim3(3, 4096, 3), 256, 0, stream>>>(q, k, v, q2, k2, v2);
    wsplit_kernel<<<dim3(12, 12, 5), 256, 0, stream>>>(
        Wq, Wk, Wv, Wl, Wf, WqT3, WkT3, WvT3, WlT3, WfT3);

    mfma_gemm<<<dim3(6, 32, 4), 256, 0, stream>>>(
        q2, k2, v2, WqT3, WkT3, WvT3, WlT3, WfT3,
        bq, bk, bv, bl, bf, outp2, qs2a, ks2a, vt2, swv, out, 0);

    sig_kernel<<<dim3(512, 8), 256, 0, stream>>>(ploc, swv, mask, sig16);

    attn_kernel<<<dim3(8, 8, 12), 256, 0, stream>>>(
        qs2a, ks2a, vt2, sig16, fused, (ushort_t*)outp2, sums);

    norm_kernel<<<dim3(24576), 256, 0, stream>>>(fused, sums);

    mfma_gemm<<<dim3(6, 32, 1), 256, 0, stream>>>(
        q2, k2, v2, WqT3, WkT3, WvT3, WlT3, WfT3,
        bq, bk, bv, bl, bf, outp2, qs2a, ks2a, vt2, swv, out, 4);
}